// Round 1
// baseline (469.370 us; speedup 1.0000x reference)
//
#include <hip/hip_runtime.h>

#define D_IN 128
#define BN_EPS 1e-5f

// ---------------------------------------------------------------------------
// Folded-weight precompute:
//  AT[0][k][j] = A1[j][k] = sum_t Wo[j][t]     * Wn[t][k]
//  AT[1][k][j] = A2[j][k] = Wo[j][128+k] + sum_t Wo[j][256+t] * Wr[t][k]
//  AT[2][k][j] = A3[j][k] = sum_t Wo[j][256+t] * Wl[t][k]
//  c1[j] = sum_t Wo[j][t]*bn[t]        (multiplied by deg[m])
//  c0[j] = sum_t Wo[j][256+t]*bl[t] + bo[j]
// ---------------------------------------------------------------------------
__global__ void combine_weights_k(const float* __restrict__ Wn, const float* __restrict__ bn,
                                  const float* __restrict__ Wl, const float* __restrict__ bl,
                                  const float* __restrict__ Wr, const float* __restrict__ Wo,
                                  const float* __restrict__ bo,
                                  float* __restrict__ AT, float* __restrict__ c1,
                                  float* __restrict__ c0) {
    int b = blockIdx.x;
    int j = threadIdx.x;   // 0..127
    if (b < 384) {
        int term = b >> 7;
        int k = b & 127;
        float acc = 0.f;
        if (term == 0) {
            for (int t = 0; t < 128; ++t) acc += Wo[j * 384 + t] * Wn[t * 128 + k];
        } else if (term == 1) {
            acc = Wo[j * 384 + 128 + k];
            for (int t = 0; t < 128; ++t) acc += Wo[j * 384 + 256 + t] * Wr[t * 128 + k];
        } else {
            for (int t = 0; t < 128; ++t) acc += Wo[j * 384 + 256 + t] * Wl[t * 128 + k];
        }
        AT[term * 16384 + k * 128 + j] = acc;
    } else {
        float a1 = 0.f, a0 = bo[j];
        for (int t = 0; t < 128; ++t) {
            a1 += Wo[j * 384 + t] * bn[t];
            a0 += Wo[j * 384 + 256 + t] * bl[t];
        }
        c1[j] = a1;
        c0[j] = a0;
    }
}

// deg histogram over concatenated [metrical | note] buckets
__global__ void hist_k(const int* __restrict__ src, const int* __restrict__ dst,
                       int* __restrict__ deg, int nE, int nM) {
    int i = blockIdx.x * blockDim.x + threadIdx.x;
    int stride = gridDim.x * blockDim.x;
    for (int e = i; e < nE; e += stride) {
        atomicAdd(&deg[dst[e]], 1);
        atomicAdd(&deg[nM + src[e]], 1);
    }
}

// 3-phase exclusive scan (chunk = 4096)
__global__ void scan1_k(const int* __restrict__ in, int* __restrict__ out,
                        int* __restrict__ blockSums, int n) {
    __shared__ int lds[256];
    int b = blockIdx.x, t = threadIdx.x;
    int base = b * 4096 + t * 16;
    int v[16];
    int s = 0;
#pragma unroll
    for (int i = 0; i < 16; ++i) { int idx = base + i; v[i] = (idx < n) ? in[idx] : 0; s += v[i]; }
    lds[t] = s;
    __syncthreads();
    for (int off = 1; off < 256; off <<= 1) {
        int add = (t >= off) ? lds[t - off] : 0;
        __syncthreads();
        lds[t] += add;
        __syncthreads();
    }
    int run = lds[t] - s;  // exclusive base for this thread
#pragma unroll
    for (int i = 0; i < 16; ++i) { int idx = base + i; if (idx < n) out[idx] = run; run += v[i]; }
    if (t == 255) blockSums[b] = lds[255];
}

__global__ void scan2_k(int* __restrict__ blockSums, int nb) {
    if (threadIdx.x == 0 && blockIdx.x == 0) {
        int run = 0;
        for (int i = 0; i < nb; ++i) { int v = blockSums[i]; blockSums[i] = run; run += v; }
    }
}

__global__ void scan3_k(int* __restrict__ off, int* __restrict__ cur,
                        const int* __restrict__ blockSums, int n, int total) {
    int i = blockIdx.x * blockDim.x + threadIdx.x;
    int stride = gridDim.x * blockDim.x;
    for (int idx = i; idx <= n; idx += stride) {
        if (idx < n) {
            int v = off[idx] + blockSums[idx >> 12];
            off[idx] = v;
            cur[idx] = v;
        } else {
            off[idx] = total;
        }
    }
}

// CSR fill: dst-buckets store partner src; src-buckets store partner dst.
__global__ void fill_k(const int* __restrict__ src, const int* __restrict__ dst,
                       int* __restrict__ cur, int* __restrict__ list, int nE, int nM) {
    int i = blockIdx.x * blockDim.x + threadIdx.x;
    int stride = gridDim.x * blockDim.x;
    for (int e = i; e < nE; e += stride) {
        int m = dst[e], s2 = src[e];
        int pd = atomicAdd(&cur[m], 1);
        list[pd] = s2;
        int ps = atomicAdd(&cur[nM + s2], 1);
        list[ps] = m;
    }
}

// XS[m] = sum of x rows over edges with dst == m  (gather, no atomics)
__global__ void gather_xs_k(const float* __restrict__ x, const int* __restrict__ off,
                            const int* __restrict__ list, float* __restrict__ XS) {
    int m = blockIdx.x, d = threadIdx.x;
    int s = off[m], e = off[m + 1];
    float acc = 0.f;
    for (int i = s; i < e; ++i) acc += x[list[i] * D_IN + d];
    XS[m * D_IN + d] = acc;
}

// H[m][j] = XS[m]@A1.T + XM[m]@A2.T + XM[m-1]@A3.T + deg[m]*c1[j] + c0[j]
// Tiled f32 GEMM: BM=128 rows x 128 cols per block, K=384 in 12 chunks of 32.
__global__ __launch_bounds__(256) void gemm_h_k(const float* __restrict__ XS,
                                                const float* __restrict__ XM,
                                                const float* __restrict__ AT,
                                                const float* __restrict__ c1,
                                                const float* __restrict__ c0,
                                                const int* __restrict__ off,
                                                float* __restrict__ H, int nM) {
    __shared__ float in_t[128][37];   // pad 37: a-reads hit 4 distinct banks
    __shared__ float wt[32][128];
    int m0 = blockIdx.x * 128;
    int tid = threadIdx.x;
    int tc = tid & 15, tr = tid >> 4;  // 16x16 thread tile; each thread 8 rows x 8 cols
    float acc[8][8];
#pragma unroll
    for (int r = 0; r < 8; ++r)
#pragma unroll
        for (int c = 0; c < 8; ++c) acc[r][c] = 0.f;

    int lr = tid >> 1;
    int lc = (tid & 1) * 16;

    for (int ch = 0; ch < 12; ++ch) {
        int term = ch >> 2;
        int kb = (ch & 3) * 32;
        // stage input tile 128x32
        {
            int gm = m0 + lr;
            const float* sp = nullptr;
            if (term == 0) {
                if (gm < nM) sp = XS + gm * D_IN + kb;
            } else if (term == 1) {
                if (gm < nM) sp = XM + gm * D_IN + kb;
            } else {
                if (gm >= 1 && gm < nM) sp = XM + (gm - 1) * D_IN + kb;
            }
            float vv[16];
            if (sp) {
#pragma unroll
                for (int q = 0; q < 4; ++q) {
                    float4 f = *(const float4*)(sp + lc + q * 4);
                    vv[q * 4 + 0] = f.x; vv[q * 4 + 1] = f.y;
                    vv[q * 4 + 2] = f.z; vv[q * 4 + 3] = f.w;
                }
            } else {
#pragma unroll
                for (int q = 0; q < 16; ++q) vv[q] = 0.f;
            }
#pragma unroll
            for (int q = 0; q < 16; ++q) in_t[lr][lc + q] = vv[q];
        }
        // stage weight tile 32x128 (already transposed: AT[term][k][j])
        {
            const float* ap = AT + term * 16384 + kb * 128;
#pragma unroll
            for (int i = 0; i < 16; ++i) {
                int idx = tid + i * 256;
                ((float*)wt)[idx] = ap[idx];
            }
        }
        __syncthreads();
#pragma unroll
        for (int kc = 0; kc < 32; ++kc) {
            float a[8];
#pragma unroll
            for (int r = 0; r < 8; ++r) a[r] = in_t[tr * 8 + r][kc];
            const float4* wrow = (const float4*)&wt[kc][0];
            float4 w0 = wrow[tc * 2], w1 = wrow[tc * 2 + 1];
            float w[8] = {w0.x, w0.y, w0.z, w0.w, w1.x, w1.y, w1.z, w1.w};
#pragma unroll
            for (int r = 0; r < 8; ++r)
#pragma unroll
                for (int c = 0; c < 8; ++c) acc[r][c] += a[r] * w[c];
        }
        __syncthreads();
    }
    // epilogue: + deg*c1 + c0
#pragma unroll
    for (int r = 0; r < 8; ++r) {
        int m = m0 + tr * 8 + r;
        if (m < nM) {
            float degv = (float)(off[m + 1] - off[m]);
            float* hp = H + m * D_IN + tc * 8;
#pragma unroll
            for (int c = 0; c < 8; ++c) {
                int j = tc * 8 + c;
                hp[c] = acc[r][c] + degv * c1[j] + c0[j];
            }
        }
    }
}

// column sums / sum-of-squares for BN (biased variance)
__global__ void bn_stats_k(const float* __restrict__ H, float* __restrict__ bnsum,
                           float* __restrict__ bnsq, int nM) {
    __shared__ float s1[256], s2[256];
    int col = threadIdx.x & 127, half = threadIdx.x >> 7;
    float s = 0.f, q = 0.f;
    for (int m = blockIdx.x * 2 + half; m < nM; m += gridDim.x * 2) {
        float v = H[m * D_IN + col];
        s += v;
        q += v * v;
    }
    s1[threadIdx.x] = s;
    s2[threadIdx.x] = q;
    __syncthreads();
    if (threadIdx.x < 128) {
        atomicAdd(&bnsum[col], s1[threadIdx.x] + s1[threadIdx.x + 128]);
        atomicAdd(&bnsq[col], s2[threadIdx.x] + s2[threadIdx.x + 128]);
    }
}

__global__ void bn_final_k(const float* __restrict__ bnsum, const float* __restrict__ bnsq,
                           const float* __restrict__ gamma, const float* __restrict__ beta,
                           float* __restrict__ scale, float* __restrict__ shift, int nM) {
    int j = threadIdx.x;
    float inv_n = 1.0f / (float)nM;
    float mean = bnsum[j] * inv_n;
    float var = bnsq[j] * inv_n - mean * mean;
    float sc = gamma[j] * rsqrtf(var + BN_EPS);
    scale[j] = sc;
    shift[j] = beta[j] - mean * sc;
}

// out[n][d] = scale[d] * sum_{e: src==n} H[dst[e]][d] + cnt_n * shift[d]
__global__ void gather_out_k(const float* __restrict__ H, const int* __restrict__ off2,
                             const int* __restrict__ list, const float* __restrict__ scale,
                             const float* __restrict__ shift, float* __restrict__ out) {
    int n = blockIdx.x, d = threadIdx.x;
    int s = off2[n], e = off2[n + 1];
    float acc = 0.f;
    for (int i = s; i < e; ++i) acc += H[list[i] * D_IN + d];
    out[n * D_IN + d] = scale[d] * acc + (float)(e - s) * shift[d];
}

extern "C" void kernel_launch(void* const* d_in, const int* in_sizes, int n_in,
                              void* d_out, int out_size, void* d_ws, size_t ws_size,
                              hipStream_t stream) {
    const float* x_metrical = (const float*)d_in[0];
    const float* x          = (const float*)d_in[1];
    const int*   edge       = (const int*)d_in[2];
    // d_in[3] = batch (unused: all-zero batch branch)
    const float* Wn    = (const float*)d_in[4];
    const float* bn    = (const float*)d_in[5];
    const float* Wl    = (const float*)d_in[6];
    const float* bl    = (const float*)d_in[7];
    const float* Wr    = (const float*)d_in[8];
    const float* Wo    = (const float*)d_in[9];
    const float* bo    = (const float*)d_in[10];
    const float* gamma = (const float*)d_in[11];
    const float* beta  = (const float*)d_in[12];
    float* out = (float*)d_out;

    int nM = in_sizes[0] / D_IN;
    int nX = in_sizes[1] / D_IN;
    int nE = in_sizes[2] / 2;
    int nTot = nM + nX;
    const int* src = edge;        // edge_index[0]
    const int* dst = edge + nE;   // edge_index[1]

    char* ws = (char*)d_ws;
    size_t o = 0;
    auto alloc = [&](size_t bytes) -> void* {
        void* p = ws + o;
        o = (o + bytes + 255) & ~(size_t)255;
        return p;
    };
    float* AT        = (float*)alloc((size_t)3 * 128 * 128 * 4);
    float* c1        = (float*)alloc(512);
    float* c0        = (float*)alloc(512);
    float* scale     = (float*)alloc(512);
    float* shift     = (float*)alloc(512);
    float* bnsum     = (float*)alloc(512);
    float* bnsq      = (float*)alloc(512);
    int*   blockSums = (int*)alloc(1024);
    int*   deg       = (int*)alloc((size_t)nTot * 4);
    int*   offs      = (int*)alloc(((size_t)nTot + 1) * 4);
    int*   cur       = (int*)alloc((size_t)nTot * 4);
    int*   list      = (int*)alloc((size_t)2 * nE * 4);
    float* XS        = (float*)alloc((size_t)nM * D_IN * 4);
    float* H         = (float*)alloc((size_t)nM * D_IN * 4);
    // total ~59.2 MB of ws

    hipMemsetAsync(deg, 0, (size_t)nTot * 4, stream);
    hipMemsetAsync(bnsum, 0, 1024, stream);  // bnsum + bnsq (adjacent 256B slots)

    combine_weights_k<<<385, 128, 0, stream>>>(Wn, bn, Wl, bl, Wr, Wo, bo, AT, c1, c0);
    hist_k<<<512, 256, 0, stream>>>(src, dst, deg, nE, nM);
    int nb = (nTot + 4095) / 4096;
    scan1_k<<<nb, 256, 0, stream>>>(deg, offs, blockSums, nTot);
    scan2_k<<<1, 64, 0, stream>>>(blockSums, nb);
    scan3_k<<<256, 256, 0, stream>>>(offs, cur, blockSums, nTot, 2 * nE);
    fill_k<<<512, 256, 0, stream>>>(src, dst, cur, list, nE, nM);
    gather_xs_k<<<nM, 128, 0, stream>>>(x, offs, list, XS);
    gemm_h_k<<<(nM + 127) / 128, 256, 0, stream>>>(XS, x_metrical, AT, c1, c0, offs, H, nM);
    bn_stats_k<<<400, 256, 0, stream>>>(H, bnsum, bnsq, nM);
    bn_final_k<<<1, 128, 0, stream>>>(bnsum, bnsq, gamma, beta, scale, shift, nM);
    gather_out_k<<<nX, 128, 0, stream>>>(H, offs + nM, list, scale, shift, out);
}

// Round 2
// 449.005 us; speedup vs baseline: 1.0454x; 1.0454x over previous
//
#include <hip/hip_runtime.h>

#define D_IN 128
#define BN_EPS 1e-5f

typedef __attribute__((ext_vector_type(8))) __bf16 bf16x8;
typedef __attribute__((ext_vector_type(8))) unsigned short ushort8;
typedef __attribute__((ext_vector_type(4))) float f32x4;
typedef unsigned short ushort_t;

__device__ inline ushort_t f2bf(float x) {
    union { float f; unsigned u; } c; c.f = x;
    unsigned r = (c.u + 0x7fffu + ((c.u >> 16) & 1u)) >> 16;  // RNE
    return (ushort_t)r;
}
__device__ inline float bf2f(ushort_t x) {
    union { unsigned u; float f; } c; c.u = ((unsigned)x) << 16;
    return c.f;
}

// f32 -> bf16 bulk convert, 8 elems/thread
__global__ void cvt_bf16_k(const float* __restrict__ in, ushort_t* __restrict__ out, int n8) {
    int i = blockIdx.x * blockDim.x + threadIdx.x;
    if (i < n8) {
        float4 f0 = ((const float4*)in)[i * 2];
        float4 f1 = ((const float4*)in)[i * 2 + 1];
        ushort8 o;
        o[0] = f2bf(f0.x); o[1] = f2bf(f0.y); o[2] = f2bf(f0.z); o[3] = f2bf(f0.w);
        o[4] = f2bf(f1.x); o[5] = f2bf(f1.y); o[6] = f2bf(f1.z); o[7] = f2bf(f1.w);
        ((ushort8*)out)[i] = o;
    }
}

// ---------------------------------------------------------------------------
// Folded weights (bf16, row-major [term][j][k]):
//  W[0][j][k] = sum_t Wo[j][t]     * Wn[t][k]
//  W[1][j][k] = Wo[j][128+k] + sum_t Wo[j][256+t] * Wr[t][k]
//  W[2][j][k] = sum_t Wo[j][256+t] * Wl[t][k]
//  c1[j] = sum_t Wo[j][t]*bn[t]   (scaled by deg[m]);  c0[j] = sum Wo[j][256+t]*bl[t] + bo[j]
// ---------------------------------------------------------------------------
__global__ void combine_weights_k(const float* __restrict__ Wn, const float* __restrict__ bn,
                                  const float* __restrict__ Wl, const float* __restrict__ bl,
                                  const float* __restrict__ Wr, const float* __restrict__ Wo,
                                  const float* __restrict__ bo,
                                  ushort_t* __restrict__ Wb, float* __restrict__ c1,
                                  float* __restrict__ c0) {
    int b = blockIdx.x;
    int j = threadIdx.x;   // 0..127
    if (b < 384) {
        int term = b >> 7;
        int k = b & 127;
        float acc = 0.f;
        if (term == 0) {
            for (int t = 0; t < 128; ++t) acc += Wo[j * 384 + t] * Wn[t * 128 + k];
        } else if (term == 1) {
            acc = Wo[j * 384 + 128 + k];
            for (int t = 0; t < 128; ++t) acc += Wo[j * 384 + 256 + t] * Wr[t * 128 + k];
        } else {
            for (int t = 0; t < 128; ++t) acc += Wo[j * 384 + 256 + t] * Wl[t * 128 + k];
        }
        Wb[term * 16384 + j * 128 + k] = f2bf(acc);
    } else {
        float a1 = 0.f, a0 = bo[j];
        for (int t = 0; t < 128; ++t) {
            a1 += Wo[j * 384 + t] * bn[t];
            a0 += Wo[j * 384 + 256 + t] * bl[t];
        }
        c1[j] = a1;
        c0[j] = a0;
    }
}

// deg histogram over concatenated [metrical | note] buckets; 1 edge/thread
__global__ void hist_k(const int* __restrict__ src, const int* __restrict__ dst,
                       int* __restrict__ deg, int nE, int nM) {
    int e = blockIdx.x * blockDim.x + threadIdx.x;
    if (e < nE) {
        atomicAdd(&deg[dst[e]], 1);
        atomicAdd(&deg[nM + src[e]], 1);
    }
}

// 3-phase exclusive scan (chunk = 4096)
__global__ void scan1_k(const int* __restrict__ in, int* __restrict__ out,
                        int* __restrict__ blockSums, int n) {
    __shared__ int lds[256];
    int b = blockIdx.x, t = threadIdx.x;
    int base = b * 4096 + t * 16;
    int v[16];
    int s = 0;
#pragma unroll
    for (int i = 0; i < 16; ++i) { int idx = base + i; v[i] = (idx < n) ? in[idx] : 0; s += v[i]; }
    lds[t] = s;
    __syncthreads();
    for (int off = 1; off < 256; off <<= 1) {
        int add = (t >= off) ? lds[t - off] : 0;
        __syncthreads();
        lds[t] += add;
        __syncthreads();
    }
    int run = lds[t] - s;
#pragma unroll
    for (int i = 0; i < 16; ++i) { int idx = base + i; if (idx < n) out[idx] = run; run += v[i]; }
    if (t == 255) blockSums[b] = lds[255];
}

__global__ void scan2_k(int* __restrict__ blockSums, int nb) {
    if (threadIdx.x == 0 && blockIdx.x == 0) {
        int run = 0;
        for (int i = 0; i < nb; ++i) { int v = blockSums[i]; blockSums[i] = run; run += v; }
    }
}

__global__ void scan3_k(int* __restrict__ off, int* __restrict__ cur,
                        const int* __restrict__ blockSums, int n, int total) {
    int i = blockIdx.x * blockDim.x + threadIdx.x;
    int stride = gridDim.x * blockDim.x;
    for (int idx = i; idx <= n; idx += stride) {
        if (idx < n) {
            int v = off[idx] + blockSums[idx >> 12];
            off[idx] = v;
            cur[idx] = v;
        } else {
            off[idx] = total;
        }
    }
}

// CSR fill: dst-buckets store partner src; src-buckets store partner dst. 1 edge/thread.
__global__ void fill_k(const int* __restrict__ src, const int* __restrict__ dst,
                       int* __restrict__ cur, int* __restrict__ list, int nE, int nM) {
    int e = blockIdx.x * blockDim.x + threadIdx.x;
    if (e < nE) {
        int m = dst[e], s2 = src[e];
        int pd = atomicAdd(&cur[m], 1);
        list[pd] = s2;
        int ps = atomicAdd(&cur[nM + s2], 1);
        list[ps] = m;
    }
}

// XS[m] = sum of x rows (bf16) over edges with dst == m; write bf16
__global__ void gather_xs_k(const ushort_t* __restrict__ xb, const int* __restrict__ off,
                            const int* __restrict__ list, ushort_t* __restrict__ XSb) {
    int m = blockIdx.x, d = threadIdx.x;
    int s = off[m], e = off[m + 1];
    float acc = 0.f;
    for (int i = s; i < e; ++i) acc += bf2f(xb[(size_t)list[i] * D_IN + d]);
    XSb[(size_t)m * D_IN + d] = f2bf(acc);
}

// H[m][j] = XS[m]@A1.T + XM[m]@A2.T + XM[m-1]@A3.T + deg[m]*c1[j] + c0[j]
// MFMA 16x16x32 bf16, no LDS: each wave = 16 rows x 128 cols, 8 j-tiles.
// A frag: row = lane&15, k = (lane>>4)*8 + i   (row-major 16B load)
// B frag: col = lane&15, k = (lane>>4)*8 + i   -> read W[term][col][k] row-major
// D:      col = lane&15, row = (lane>>4)*4 + reg
__global__ __launch_bounds__(256) void gemm_h_k(const ushort_t* __restrict__ XSb,
                                                const ushort_t* __restrict__ XMb,
                                                const ushort_t* __restrict__ Wb,
                                                const float* __restrict__ c1,
                                                const float* __restrict__ c0,
                                                const int* __restrict__ off,
                                                ushort_t* __restrict__ Hb, int nM) {
    int wave = threadIdx.x >> 6, lane = threadIdx.x & 63;
    int m0 = blockIdx.x * 64 + wave * 16;
    if (m0 >= nM) return;
    int rl = lane & 15, kg = lane >> 4;
    f32x4 acc[8];
#pragma unroll
    for (int jt = 0; jt < 8; ++jt) acc[jt] = (f32x4){0.f, 0.f, 0.f, 0.f};
    int arow = m0 + rl;
#pragma unroll
    for (int term = 0; term < 3; ++term) {
        const ushort_t* xp = (term == 0) ? XSb : XMb;
        int r2 = (term == 2) ? (arow - 1) : arow;
        bool valid = (r2 >= 0) && (arow < nM);
        const ushort_t* rp = xp + (size_t)r2 * D_IN;
        const ushort_t* wbase = Wb + term * 16384 + rl * 128;
#pragma unroll
        for (int kc = 0; kc < 4; ++kc) {
            int kb = kc * 32 + kg * 8;
            bf16x8 a;
            if (valid) {
                a = *reinterpret_cast<const bf16x8*>(rp + kb);
            } else {
#pragma unroll
                for (int i = 0; i < 8; ++i) a[i] = (__bf16)0.f;
            }
#pragma unroll
            for (int jt = 0; jt < 8; ++jt) {
                bf16x8 b = *reinterpret_cast<const bf16x8*>(wbase + jt * 2048 + kb);
                acc[jt] = __builtin_amdgcn_mfma_f32_16x16x32_bf16(a, b, acc[jt], 0, 0, 0);
            }
        }
    }
    float cc1[8], cc0[8];
#pragma unroll
    for (int jt = 0; jt < 8; ++jt) { cc1[jt] = c1[jt * 16 + rl]; cc0[jt] = c0[jt * 16 + rl]; }
#pragma unroll
    for (int r = 0; r < 4; ++r) {
        int rowd = m0 + kg * 4 + r;
        if (rowd < nM) {
            float degv = (float)(off[rowd + 1] - off[rowd]);
            ushort_t* hp = Hb + (size_t)rowd * D_IN;
#pragma unroll
            for (int jt = 0; jt < 8; ++jt)
                hp[jt * 16 + rl] = f2bf(acc[jt][r] + degv * cc1[jt] + cc0[jt]);
        }
    }
}

// column sums / sum-of-squares for BN (reads bf16 H)
__global__ void bn_stats_k(const ushort_t* __restrict__ Hb, float* __restrict__ bnsum,
                           float* __restrict__ bnsq, int nM) {
    __shared__ float s1[256], s2[256];
    int col = threadIdx.x & 127, half = threadIdx.x >> 7;
    float s = 0.f, q = 0.f;
    for (int m = blockIdx.x * 2 + half; m < nM; m += gridDim.x * 2) {
        float v = bf2f(Hb[(size_t)m * D_IN + col]);
        s += v;
        q += v * v;
    }
    s1[threadIdx.x] = s;
    s2[threadIdx.x] = q;
    __syncthreads();
    if (threadIdx.x < 128) {
        atomicAdd(&bnsum[col], s1[threadIdx.x] + s1[threadIdx.x + 128]);
        atomicAdd(&bnsq[col], s2[threadIdx.x] + s2[threadIdx.x + 128]);
    }
}

__global__ void bn_final_k(const float* __restrict__ bnsum, const float* __restrict__ bnsq,
                           const float* __restrict__ gamma, const float* __restrict__ beta,
                           float* __restrict__ scale, float* __restrict__ shift, int nM) {
    int j = threadIdx.x;
    float inv_n = 1.0f / (float)nM;
    float mean = bnsum[j] * inv_n;
    float var = bnsq[j] * inv_n - mean * mean;
    float sc = gamma[j] * rsqrtf(var + BN_EPS);
    scale[j] = sc;
    shift[j] = beta[j] - mean * sc;
}

// out[n][d] = scale[d] * sum_{e: src==n} H[dst[e]][d] + cnt_n * shift[d]
__global__ void gather_out_k(const ushort_t* __restrict__ Hb, const int* __restrict__ off2,
                             const int* __restrict__ list, const float* __restrict__ scale,
                             const float* __restrict__ shift, float* __restrict__ out) {
    int n = blockIdx.x, d = threadIdx.x;
    int s = off2[n], e = off2[n + 1];
    float acc = 0.f;
    for (int i = s; i < e; ++i) acc += bf2f(Hb[(size_t)list[i] * D_IN + d]);
    out[(size_t)n * D_IN + d] = scale[d] * acc + (float)(e - s) * shift[d];
}

extern "C" void kernel_launch(void* const* d_in, const int* in_sizes, int n_in,
                              void* d_out, int out_size, void* d_ws, size_t ws_size,
                              hipStream_t stream) {
    const float* x_metrical = (const float*)d_in[0];
    const float* x          = (const float*)d_in[1];
    const int*   edge       = (const int*)d_in[2];
    // d_in[3] = batch (unused: all-zero batch branch)
    const float* Wn    = (const float*)d_in[4];
    const float* bn    = (const float*)d_in[5];
    const float* Wl    = (const float*)d_in[6];
    const float* bl    = (const float*)d_in[7];
    const float* Wr    = (const float*)d_in[8];
    const float* Wo    = (const float*)d_in[9];
    const float* bo    = (const float*)d_in[10];
    const float* gamma = (const float*)d_in[11];
    const float* beta  = (const float*)d_in[12];
    float* out = (float*)d_out;

    int nM = in_sizes[0] / D_IN;
    int nX = in_sizes[1] / D_IN;
    int nE = in_sizes[2] / 2;
    int nTot = nM + nX;
    const int* src = edge;        // edge_index[0]
    const int* dst = edge + nE;   // edge_index[1]

    char* ws = (char*)d_ws;
    size_t o = 0;
    auto alloc = [&](size_t bytes) -> void* {
        void* p = ws + o;
        o = (o + bytes + 255) & ~(size_t)255;
        return p;
    };
    ushort_t* Wb        = (ushort_t*)alloc((size_t)3 * 128 * 128 * 2);
    float*    c1        = (float*)alloc(512);
    float*    c0        = (float*)alloc(512);
    float*    scale     = (float*)alloc(512);
    float*    shift     = (float*)alloc(512);
    float*    bnsum     = (float*)alloc(512);
    float*    bnsq      = (float*)alloc(512);
    int*      blockSums = (int*)alloc(1024);
    int*      deg       = (int*)alloc((size_t)nTot * 4);
    int*      offs      = (int*)alloc(((size_t)nTot + 1) * 4);
    int*      cur       = (int*)alloc((size_t)nTot * 4);
    int*      list      = (int*)alloc((size_t)2 * nE * 4);
    ushort_t* XSb       = (ushort_t*)alloc((size_t)nM * D_IN * 2);
    ushort_t* xmb       = (ushort_t*)alloc((size_t)nM * D_IN * 2);
    ushort_t* xb        = (ushort_t*)alloc((size_t)nX * D_IN * 2);
    // Hb aliases xb: xb is dead after gather_xs_k; Hb written by gemm_h_k after that.
    ushort_t* Hb        = xb;
    // total ~86 MB of ws

    hipMemsetAsync(deg, 0, (size_t)nTot * 4, stream);
    hipMemsetAsync(bnsum, 0, 1024, stream);  // bnsum + bnsq (adjacent 256B slots)

    combine_weights_k<<<385, 128, 0, stream>>>(Wn, bn, Wl, bl, Wr, Wo, bo, Wb, c1, c0);
    {
        int n8 = nX * D_IN / 8;
        cvt_bf16_k<<<(n8 + 255) / 256, 256, 0, stream>>>(x, xb, n8);
        int m8 = nM * D_IN / 8;
        cvt_bf16_k<<<(m8 + 255) / 256, 256, 0, stream>>>(x_metrical, xmb, m8);
    }
    hist_k<<<(nE + 255) / 256, 256, 0, stream>>>(src, dst, deg, nE, nM);
    int nb = (nTot + 4095) / 4096;
    scan1_k<<<nb, 256, 0, stream>>>(deg, offs, blockSums, nTot);
    scan2_k<<<1, 64, 0, stream>>>(blockSums, nb);
    scan3_k<<<256, 256, 0, stream>>>(offs, cur, blockSums, nTot, 2 * nE);
    fill_k<<<(nE + 255) / 256, 256, 0, stream>>>(src, dst, cur, list, nE, nM);
    gather_xs_k<<<nM, 128, 0, stream>>>(xb, offs, list, XSb);
    gemm_h_k<<<(nM + 63) / 64, 256, 0, stream>>>(XSb, xmb, Wb, c1, c0, offs, Hb, nM);
    bn_stats_k<<<512, 256, 0, stream>>>(Hb, bnsum, bnsq, nM);
    bn_final_k<<<1, 128, 0, stream>>>(bnsum, bnsq, gamma, beta, scale, shift, nM);
    gather_out_k<<<nX, 128, 0, stream>>>(Hb, offs + nM, list, scale, shift, out);
}

// Round 3
// 386.906 us; speedup vs baseline: 1.2131x; 1.1605x over previous
//
#include <hip/hip_runtime.h>

#define D_IN 128
#define BN_EPS 1e-5f

typedef __attribute__((ext_vector_type(8))) __bf16 bf16x8;
typedef __attribute__((ext_vector_type(8))) unsigned short ushort8;
typedef __attribute__((ext_vector_type(4))) float f32x4;
typedef unsigned short ushort_t;

__device__ inline ushort_t f2bf(float x) {
    union { float f; unsigned u; } c; c.f = x;
    unsigned r = (c.u + 0x7fffu + ((c.u >> 16) & 1u)) >> 16;  // RNE
    return (ushort_t)r;
}
__device__ inline float bf2f(ushort_t x) {
    union { unsigned u; float f; } c; c.u = ((unsigned)x) << 16;
    return c.f;
}
// low/high bf16 of a packed uint -> float
__device__ inline float lof(unsigned v) {
    union { unsigned u; float f; } c; c.u = v << 16;
    return c.f;
}
__device__ inline float hif(unsigned v) {
    union { unsigned u; float f; } c; c.u = v & 0xffff0000u;
    return c.f;
}

// f32 -> bf16 bulk convert, 8 elems/thread
__global__ void cvt_bf16_k(const float* __restrict__ in, ushort_t* __restrict__ out, int n8) {
    int i = blockIdx.x * blockDim.x + threadIdx.x;
    if (i < n8) {
        float4 f0 = ((const float4*)in)[i * 2];
        float4 f1 = ((const float4*)in)[i * 2 + 1];
        ushort8 o;
        o[0] = f2bf(f0.x); o[1] = f2bf(f0.y); o[2] = f2bf(f0.z); o[3] = f2bf(f0.w);
        o[4] = f2bf(f1.x); o[5] = f2bf(f1.y); o[6] = f2bf(f1.z); o[7] = f2bf(f1.w);
        ((ushort8*)out)[i] = o;
    }
}

// ---------------------------------------------------------------------------
// Folded weights (bf16, row-major [term][j][k]) + bias vectors (see round 1).
// ---------------------------------------------------------------------------
__global__ void combine_weights_k(const float* __restrict__ Wn, const float* __restrict__ bn,
                                  const float* __restrict__ Wl, const float* __restrict__ bl,
                                  const float* __restrict__ Wr, const float* __restrict__ Wo,
                                  const float* __restrict__ bo,
                                  ushort_t* __restrict__ Wb, float* __restrict__ c1,
                                  float* __restrict__ c0) {
    int b = blockIdx.x;
    int j = threadIdx.x;   // 0..127
    if (b < 384) {
        int term = b >> 7;
        int k = b & 127;
        float acc = 0.f;
        if (term == 0) {
            for (int t = 0; t < 128; ++t) acc += Wo[j * 384 + t] * Wn[t * 128 + k];
        } else if (term == 1) {
            acc = Wo[j * 384 + 128 + k];
            for (int t = 0; t < 128; ++t) acc += Wo[j * 384 + 256 + t] * Wr[t * 128 + k];
        } else {
            for (int t = 0; t < 128; ++t) acc += Wo[j * 384 + 256 + t] * Wl[t * 128 + k];
        }
        Wb[term * 16384 + j * 128 + k] = f2bf(acc);
    } else {
        float a1 = 0.f, a0 = bo[j];
        for (int t = 0; t < 128; ++t) {
            a1 += Wo[j * 384 + t] * bn[t];
            a0 += Wo[j * 384 + 256 + t] * bl[t];
        }
        c1[j] = a1;
        c0[j] = a0;
    }
}

// deg histogram; 1 thread per (edge, direction)
__global__ void hist_k(const int* __restrict__ src, const int* __restrict__ dst,
                       int* __restrict__ deg, int nE, int nM) {
    int t = blockIdx.x * blockDim.x + threadIdx.x;
    if (t < nE) {
        atomicAdd(&deg[dst[t]], 1);
    } else if (t < 2 * nE) {
        atomicAdd(&deg[nM + src[t - nE]], 1);
    }
}

// 3-phase exclusive scan (chunk = 4096)
__global__ void scan1_k(const int* __restrict__ in, int* __restrict__ out,
                        int* __restrict__ blockSums, int n) {
    __shared__ int lds[256];
    int b = blockIdx.x, t = threadIdx.x;
    int base = b * 4096 + t * 16;
    int v[16];
    int s = 0;
#pragma unroll
    for (int i = 0; i < 16; ++i) { int idx = base + i; v[i] = (idx < n) ? in[idx] : 0; s += v[i]; }
    lds[t] = s;
    __syncthreads();
    for (int off = 1; off < 256; off <<= 1) {
        int add = (t >= off) ? lds[t - off] : 0;
        __syncthreads();
        lds[t] += add;
        __syncthreads();
    }
    int run = lds[t] - s;
#pragma unroll
    for (int i = 0; i < 16; ++i) { int idx = base + i; if (idx < n) out[idx] = run; run += v[i]; }
    if (t == 255) blockSums[b] = lds[255];
}

__global__ void scan2_k(int* __restrict__ blockSums, int nb) {
    if (threadIdx.x == 0 && blockIdx.x == 0) {
        int run = 0;
        for (int i = 0; i < nb; ++i) { int v = blockSums[i]; blockSums[i] = run; run += v; }
    }
}

__global__ void scan3_k(int* __restrict__ off, int* __restrict__ cur,
                        const int* __restrict__ blockSums, int n, int total) {
    int i = blockIdx.x * blockDim.x + threadIdx.x;
    int stride = gridDim.x * blockDim.x;
    for (int idx = i; idx <= n; idx += stride) {
        if (idx < n) {
            int v = off[idx] + blockSums[idx >> 12];
            off[idx] = v;
            cur[idx] = v;
        } else {
            off[idx] = total;
        }
    }
}

// CSR fill; 1 thread per (edge, direction)
__global__ void fill_k(const int* __restrict__ src, const int* __restrict__ dst,
                       int* __restrict__ cur, int* __restrict__ list, int nE, int nM) {
    int t = blockIdx.x * blockDim.x + threadIdx.x;
    if (t < nE) {
        int m = dst[t], s2 = src[t];
        int p = atomicAdd(&cur[m], 1);
        list[p] = s2;
    } else if (t < 2 * nE) {
        int e = t - nE;
        int m = dst[e], s2 = src[e];
        int p = atomicAdd(&cur[nM + s2], 1);
        list[p] = m;
    }
}

// XS[m] = sum of x rows (bf16) over edges with dst == m.
// One note per wave; lane covers 2 cols via packed uint; 4-way unrolled MLP loop.
__global__ __launch_bounds__(256) void gather_xs_k(const unsigned* __restrict__ x2,
                                                   const int* __restrict__ off,
                                                   const int* __restrict__ list,
                                                   unsigned* __restrict__ XS2, int nM) {
    int m = blockIdx.x * 4 + (threadIdx.x >> 6);
    if (m >= nM) return;
    int lane = threadIdx.x & 63;
    int s = off[m], e = off[m + 1];
    float a0 = 0.f, a1 = 0.f;
    int i = s;
    while (i + 4 <= e) {
        int r0 = list[i], r1 = list[i + 1], r2 = list[i + 2], r3 = list[i + 3];
        unsigned v0 = x2[(size_t)r0 * 64 + lane];
        unsigned v1 = x2[(size_t)r1 * 64 + lane];
        unsigned v2 = x2[(size_t)r2 * 64 + lane];
        unsigned v3 = x2[(size_t)r3 * 64 + lane];
        a0 += lof(v0) + lof(v1) + lof(v2) + lof(v3);
        a1 += hif(v0) + hif(v1) + hif(v2) + hif(v3);
        i += 4;
    }
    while (i < e) {
        unsigned v = x2[(size_t)list[i] * 64 + lane];
        a0 += lof(v); a1 += hif(v);
        ++i;
    }
    XS2[(size_t)m * 64 + lane] = (unsigned)f2bf(a0) | ((unsigned)f2bf(a1) << 16);
}

// H[m][j] = XS[m]@A1.T + XM[m]@A2.T + XM[m-1]@A3.T + deg[m]*c1[j] + c0[j]
// MFMA 16x16x32 bf16, no LDS: each wave = 16 rows x 128 cols, 8 j-tiles.
__global__ __launch_bounds__(256) void gemm_h_k(const ushort_t* __restrict__ XSb,
                                                const ushort_t* __restrict__ XMb,
                                                const ushort_t* __restrict__ Wb,
                                                const float* __restrict__ c1,
                                                const float* __restrict__ c0,
                                                const int* __restrict__ off,
                                                ushort_t* __restrict__ Hb, int nM) {
    int wave = threadIdx.x >> 6, lane = threadIdx.x & 63;
    int m0 = blockIdx.x * 64 + wave * 16;
    if (m0 >= nM) return;
    int rl = lane & 15, kg = lane >> 4;
    f32x4 acc[8];
#pragma unroll
    for (int jt = 0; jt < 8; ++jt) acc[jt] = (f32x4){0.f, 0.f, 0.f, 0.f};
    int arow = m0 + rl;
#pragma unroll
    for (int term = 0; term < 3; ++term) {
        const ushort_t* xp = (term == 0) ? XSb : XMb;
        int r2 = (term == 2) ? (arow - 1) : arow;
        bool valid = (r2 >= 0) && (arow < nM);
        const ushort_t* rp = xp + (size_t)r2 * D_IN;
        const ushort_t* wbase = Wb + term * 16384 + rl * 128;
#pragma unroll
        for (int kc = 0; kc < 4; ++kc) {
            int kb = kc * 32 + kg * 8;
            bf16x8 a;
            if (valid) {
                a = *reinterpret_cast<const bf16x8*>(rp + kb);
            } else {
#pragma unroll
                for (int i = 0; i < 8; ++i) a[i] = (__bf16)0.f;
            }
#pragma unroll
            for (int jt = 0; jt < 8; ++jt) {
                bf16x8 b = *reinterpret_cast<const bf16x8*>(wbase + jt * 2048 + kb);
                acc[jt] = __builtin_amdgcn_mfma_f32_16x16x32_bf16(a, b, acc[jt], 0, 0, 0);
            }
        }
    }
    float cc1[8], cc0[8];
#pragma unroll
    for (int jt = 0; jt < 8; ++jt) { cc1[jt] = c1[jt * 16 + rl]; cc0[jt] = c0[jt * 16 + rl]; }
#pragma unroll
    for (int r = 0; r < 4; ++r) {
        int rowd = m0 + kg * 4 + r;
        if (rowd < nM) {
            float degv = (float)(off[rowd + 1] - off[rowd]);
            ushort_t* hp = Hb + (size_t)rowd * D_IN;
#pragma unroll
            for (int jt = 0; jt < 8; ++jt)
                hp[jt * 16 + rl] = f2bf(acc[jt][r] + degv * cc1[jt] + cc0[jt]);
        }
    }
}

// column sums / sum-of-squares for BN (reads bf16 H)
__global__ void bn_stats_k(const ushort_t* __restrict__ Hb, float* __restrict__ bnsum,
                           float* __restrict__ bnsq, int nM) {
    __shared__ float s1[256], s2[256];
    int col = threadIdx.x & 127, half = threadIdx.x >> 7;
    float s = 0.f, q = 0.f;
    for (int m = blockIdx.x * 2 + half; m < nM; m += gridDim.x * 2) {
        float v = bf2f(Hb[(size_t)m * D_IN + col]);
        s += v;
        q += v * v;
    }
    s1[threadIdx.x] = s;
    s2[threadIdx.x] = q;
    __syncthreads();
    if (threadIdx.x < 128) {
        atomicAdd(&bnsum[col], s1[threadIdx.x] + s1[threadIdx.x + 128]);
        atomicAdd(&bnsq[col], s2[threadIdx.x] + s2[threadIdx.x + 128]);
    }
}

__global__ void bn_final_k(const float* __restrict__ bnsum, const float* __restrict__ bnsq,
                           const float* __restrict__ gamma, const float* __restrict__ beta,
                           float* __restrict__ scale, float* __restrict__ shift, int nM) {
    int j = threadIdx.x;
    float inv_n = 1.0f / (float)nM;
    float mean = bnsum[j] * inv_n;
    float var = bnsq[j] * inv_n - mean * mean;
    float sc = gamma[j] * rsqrtf(var + BN_EPS);
    scale[j] = sc;
    shift[j] = beta[j] - mean * sc;
}

// out[n][d] = scale[d] * sum_{e: src==n} H[dst[e]][d] + cnt_n * shift[d]
// One note per wave; lane covers 2 cols; 4-way unrolled MLP loop.
__global__ __launch_bounds__(256) void gather_out_k(const unsigned* __restrict__ H2,
                                                    const int* __restrict__ off2,
                                                    const int* __restrict__ list,
                                                    const float* __restrict__ scale,
                                                    const float* __restrict__ shift,
                                                    float* __restrict__ out, int nX) {
    int n = blockIdx.x * 4 + (threadIdx.x >> 6);
    if (n >= nX) return;
    int lane = threadIdx.x & 63;
    int s = off2[n], e = off2[n + 1];
    float a0 = 0.f, a1 = 0.f;
    int i = s;
    while (i + 4 <= e) {
        int r0 = list[i], r1 = list[i + 1], r2 = list[i + 2], r3 = list[i + 3];
        unsigned v0 = H2[(size_t)r0 * 64 + lane];
        unsigned v1 = H2[(size_t)r1 * 64 + lane];
        unsigned v2 = H2[(size_t)r2 * 64 + lane];
        unsigned v3 = H2[(size_t)r3 * 64 + lane];
        a0 += lof(v0) + lof(v1) + lof(v2) + lof(v3);
        a1 += hif(v0) + hif(v1) + hif(v2) + hif(v3);
        i += 4;
    }
    while (i < e) {
        unsigned v = H2[(size_t)list[i] * 64 + lane];
        a0 += lof(v); a1 += hif(v);
        ++i;
    }
    float2 sc = ((const float2*)scale)[lane];
    float2 sh = ((const float2*)shift)[lane];
    float cnt = (float)(e - s);
    float2 o;
    o.x = sc.x * a0 + cnt * sh.x;
    o.y = sc.y * a1 + cnt * sh.y;
    ((float2*)out)[(size_t)n * 64 + lane] = o;
}

extern "C" void kernel_launch(void* const* d_in, const int* in_sizes, int n_in,
                              void* d_out, int out_size, void* d_ws, size_t ws_size,
                              hipStream_t stream) {
    const float* x_metrical = (const float*)d_in[0];
    const float* x          = (const float*)d_in[1];
    const int*   edge       = (const int*)d_in[2];
    // d_in[3] = batch (unused: all-zero batch branch)
    const float* Wn    = (const float*)d_in[4];
    const float* bn    = (const float*)d_in[5];
    const float* Wl    = (const float*)d_in[6];
    const float* bl    = (const float*)d_in[7];
    const float* Wr    = (const float*)d_in[8];
    const float* Wo    = (const float*)d_in[9];
    const float* bo    = (const float*)d_in[10];
    const float* gamma = (const float*)d_in[11];
    const float* beta  = (const float*)d_in[12];
    float* out = (float*)d_out;

    int nM = in_sizes[0] / D_IN;
    int nX = in_sizes[1] / D_IN;
    int nE = in_sizes[2] / 2;
    int nTot = nM + nX;
    const int* src = edge;        // edge_index[0]
    const int* dst = edge + nE;   // edge_index[1]

    char* ws = (char*)d_ws;
    size_t o = 0;
    auto alloc = [&](size_t bytes) -> void* {
        void* p = ws + o;
        o = (o + bytes + 255) & ~(size_t)255;
        return p;
    };
    ushort_t* Wb        = (ushort_t*)alloc((size_t)3 * 128 * 128 * 2);
    float*    c1        = (float*)alloc(512);
    float*    c0        = (float*)alloc(512);
    float*    scale     = (float*)alloc(512);
    float*    shift     = (float*)alloc(512);
    float*    bnsum     = (float*)alloc(512);
    float*    bnsq      = (float*)alloc(512);
    int*      blockSums = (int*)alloc(1024);
    int*      deg       = (int*)alloc((size_t)nTot * 4);
    int*      offs      = (int*)alloc(((size_t)nTot + 1) * 4);
    int*      cur       = (int*)alloc((size_t)nTot * 4);
    int*      list      = (int*)alloc((size_t)2 * nE * 4);
    ushort_t* XSb       = (ushort_t*)alloc((size_t)nM * D_IN * 2);
    ushort_t* xmb       = (ushort_t*)alloc((size_t)nM * D_IN * 2);
    ushort_t* xb        = (ushort_t*)alloc((size_t)nX * D_IN * 2);
    // Hb aliases xb: xb is dead after gather_xs_k; Hb written by gemm_h_k after that.
    ushort_t* Hb        = xb;

    hipMemsetAsync(deg, 0, (size_t)nTot * 4, stream);
    hipMemsetAsync(bnsum, 0, 1024, stream);  // bnsum + bnsq (adjacent 256B slots)

    combine_weights_k<<<385, 128, 0, stream>>>(Wn, bn, Wl, bl, Wr, Wo, bo, Wb, c1, c0);
    {
        int n8 = nX * D_IN / 8;
        cvt_bf16_k<<<(n8 + 255) / 256, 256, 0, stream>>>(x, xb, n8);
        int m8 = nM * D_IN / 8;
        cvt_bf16_k<<<(m8 + 255) / 256, 256, 0, stream>>>(x_metrical, xmb, m8);
    }
    hist_k<<<(2 * nE + 255) / 256, 256, 0, stream>>>(src, dst, deg, nE, nM);
    int nb = (nTot + 4095) / 4096;
    scan1_k<<<nb, 256, 0, stream>>>(deg, offs, blockSums, nTot);
    scan2_k<<<1, 64, 0, stream>>>(blockSums, nb);
    scan3_k<<<256, 256, 0, stream>>>(offs, cur, blockSums, nTot, 2 * nE);
    fill_k<<<(2 * nE + 255) / 256, 256, 0, stream>>>(src, dst, cur, list, nE, nM);
    gather_xs_k<<<(nM + 3) / 4, 256, 0, stream>>>((const unsigned*)xb, offs, list,
                                                  (unsigned*)XSb, nM);
    gemm_h_k<<<(nM + 63) / 64, 256, 0, stream>>>(XSb, xmb, Wb, c1, c0, offs, Hb, nM);
    bn_stats_k<<<512, 256, 0, stream>>>(Hb, bnsum, bnsq, nM);
    bn_final_k<<<1, 128, 0, stream>>>(bnsum, bnsq, gamma, beta, scale, shift, nM);
    gather_out_k<<<(nX + 3) / 4, 256, 0, stream>>>((const unsigned*)Hb, offs + nM, list,
                                                   scale, shift, out, nX);
}

// Round 4
// 244.472 us; speedup vs baseline: 1.9199x; 1.5826x over previous
//
#include <hip/hip_runtime.h>

#define D_IN 128
#define BN_EPS 1e-5f
#define BIN_SHIFT 8            // 256 buckets per bin
#define MAXBIN 1024            // supports nTot <= 262144

typedef __attribute__((ext_vector_type(8))) __bf16 bf16x8;
typedef __attribute__((ext_vector_type(8))) unsigned short ushort8;
typedef __attribute__((ext_vector_type(4))) float f32x4;
typedef unsigned short ushort_t;

__device__ inline ushort_t f2bf(float x) {
    union { float f; unsigned u; } c; c.f = x;
    unsigned r = (c.u + 0x7fffu + ((c.u >> 16) & 1u)) >> 16;  // RNE
    return (ushort_t)r;
}
__device__ inline float bf2f(ushort_t x) {
    union { unsigned u; float f; } c; c.u = ((unsigned)x) << 16;
    return c.f;
}
__device__ inline float lof(unsigned v) {
    union { unsigned u; float f; } c; c.u = v << 16;
    return c.f;
}
__device__ inline float hif(unsigned v) {
    union { unsigned u; float f; } c; c.u = v & 0xffff0000u;
    return c.f;
}

// f32 -> bf16 bulk convert for two arrays in one launch, 8 elems/thread
__global__ void cvt2_k(const float* __restrict__ a, const float* __restrict__ b,
                       ushort_t* __restrict__ oa, ushort_t* __restrict__ ob,
                       int n8a, int n8b) {
    int i = blockIdx.x * blockDim.x + threadIdx.x;
    const float* in; ushort_t* out; int k;
    if (i < n8a) { in = a; out = oa; k = i; }
    else if (i < n8a + n8b) { in = b; out = ob; k = i - n8a; }
    else return;
    float4 f0 = ((const float4*)in)[k * 2];
    float4 f1 = ((const float4*)in)[k * 2 + 1];
    ushort8 o;
    o[0] = f2bf(f0.x); o[1] = f2bf(f0.y); o[2] = f2bf(f0.z); o[3] = f2bf(f0.w);
    o[4] = f2bf(f1.x); o[5] = f2bf(f1.y); o[6] = f2bf(f1.z); o[7] = f2bf(f1.w);
    ((ushort8*)out)[k] = o;
}

// ---------------------------------------------------------------------------
// Folded weights (bf16, row-major [term][j][k]) + bias vectors.
// ---------------------------------------------------------------------------
__global__ void combine_weights_k(const float* __restrict__ Wn, const float* __restrict__ bn,
                                  const float* __restrict__ Wl, const float* __restrict__ bl,
                                  const float* __restrict__ Wr, const float* __restrict__ Wo,
                                  const float* __restrict__ bo,
                                  ushort_t* __restrict__ Wb, float* __restrict__ c1,
                                  float* __restrict__ c0) {
    int b = blockIdx.x;
    int j = threadIdx.x;   // 0..127
    if (b < 384) {
        int term = b >> 7;
        int k = b & 127;
        float acc = 0.f;
        if (term == 0) {
            for (int t = 0; t < 128; ++t) acc += Wo[j * 384 + t] * Wn[t * 128 + k];
        } else if (term == 1) {
            acc = Wo[j * 384 + 128 + k];
            for (int t = 0; t < 128; ++t) acc += Wo[j * 384 + 256 + t] * Wr[t * 128 + k];
        } else {
            for (int t = 0; t < 128; ++t) acc += Wo[j * 384 + 256 + t] * Wl[t * 128 + k];
        }
        Wb[term * 16384 + j * 128 + k] = f2bf(acc);
    } else {
        float a1 = 0.f, a0 = bo[j];
        for (int t = 0; t < 128; ++t) {
            a1 += Wo[j * 384 + t] * bn[t];
            a0 += Wo[j * 384 + 256 + t] * bl[t];
        }
        c1[j] = a1;
        c0[j] = a0;
    }
}

// ------------------- two-level CSR build (counting sort) -------------------
// pair t: key = t<nE ? dst[t] : nM+src[t-nE];  val = t<nE ? src[t] : dst[t-nE]
// bin = key >> BIN_SHIFT.  packed = (localKey << 20) | val   (val < 2^20)

__global__ __launch_bounds__(256) void bin_hist_k(const int* __restrict__ src,
                                                  const int* __restrict__ dst,
                                                  int* __restrict__ binCnt,
                                                  int nE, int nM, int nBin) {
    __shared__ int h[MAXBIN];
    int t = threadIdx.x;
    for (int i = t; i < nBin; i += 256) h[i] = 0;
    __syncthreads();
    int total = 2 * nE;
    int per = (total + gridDim.x - 1) / gridDim.x;
    int lo = blockIdx.x * per, hi = min(lo + per, total);
    for (int i = lo + t; i < hi; i += 256) {
        int key = (i < nE) ? dst[i] : (nM + src[i - nE]);
        atomicAdd(&h[key >> BIN_SHIFT], 1);
    }
    __syncthreads();
    for (int i = t; i < nBin; i += 256) {
        int v = h[i];
        if (v) atomicAdd(&binCnt[i], v);
    }
}

__global__ __launch_bounds__(1024) void bin_scan_k(const int* __restrict__ binCnt,
                                                   int* __restrict__ binBase,
                                                   int* __restrict__ binCursor,
                                                   int* __restrict__ offs,
                                                   int nBin, int nTot, int total2E) {
    __shared__ int sc[1024];
    int t = threadIdx.x;
    int v = (t < nBin) ? binCnt[t] : 0;
    sc[t] = v;
    __syncthreads();
    for (int off = 1; off < 1024; off <<= 1) {
        int a = (t >= off) ? sc[t - off] : 0;
        __syncthreads();
        sc[t] += a;
        __syncthreads();
    }
    int excl = sc[t] - v;
    if (t <= nBin) binBase[t] = excl;          // binBase[nBin] == total
    if (t < nBin) binCursor[t] = excl;
    if (t == nBin) offs[nTot] = total2E;
}

__global__ __launch_bounds__(256) void bin_scatter_k(const int* __restrict__ src,
                                                     const int* __restrict__ dst,
                                                     int* __restrict__ binCursor,
                                                     unsigned* __restrict__ binned,
                                                     int nE, int nM, int nBin) {
    __shared__ int h[MAXBIN];
    __shared__ int base[MAXBIN];
    int t = threadIdx.x;
    for (int i = t; i < nBin; i += 256) h[i] = 0;
    __syncthreads();
    int total = 2 * nE;
    int per = (total + gridDim.x - 1) / gridDim.x;
    int lo = blockIdx.x * per, hi = min(lo + per, total);
    for (int i = lo + t; i < hi; i += 256) {
        int key = (i < nE) ? dst[i] : (nM + src[i - nE]);
        atomicAdd(&h[key >> BIN_SHIFT], 1);
    }
    __syncthreads();
    for (int i = t; i < nBin; i += 256) {
        int c = h[i];
        base[i] = c ? atomicAdd(&binCursor[i], c) : 0;
        h[i] = 0;  // reuse as local cursor
    }
    __syncthreads();
    for (int i = lo + t; i < hi; i += 256) {
        int key, val;
        if (i < nE) { key = dst[i]; val = src[i]; }
        else        { key = nM + src[i - nE]; val = dst[i - nE]; }
        int b = key >> BIN_SHIFT;
        int p = base[b] + atomicAdd(&h[b], 1);
        binned[p] = ((unsigned)(key & ((1 << BIN_SHIFT) - 1)) << 20) | (unsigned)val;
    }
}

// one workgroup per bin: local counting sort -> offs + list
__global__ __launch_bounds__(256) void bucket_sort_k(const unsigned* __restrict__ binned,
                                                     const int* __restrict__ binBase,
                                                     int* __restrict__ offs,
                                                     int* __restrict__ list, int nTot) {
    __shared__ int hist[256];
    __shared__ int sc[256];
    __shared__ int cur[256];
    int b = blockIdx.x;
    int base = binBase[b], end = binBase[b + 1];
    int n = end - base;
    int t = threadIdx.x;
    hist[t] = 0;
    __syncthreads();
    for (int i = t; i < n; i += 256) atomicAdd(&hist[binned[base + i] >> 20], 1);
    __syncthreads();
    int v = hist[t];
    sc[t] = v;
    __syncthreads();
    for (int off = 1; off < 256; off <<= 1) {
        int a = (t >= off) ? sc[t - off] : 0;
        __syncthreads();
        sc[t] += a;
        __syncthreads();
    }
    int excl = sc[t] - v;
    int bucket = (b << BIN_SHIFT) + t;
    if (bucket < nTot) offs[bucket] = base + excl;
    cur[t] = excl;
    __syncthreads();
    for (int i = t; i < n; i += 256) {
        unsigned p = binned[base + i];
        int lb = p >> 20;
        int pos = atomicAdd(&cur[lb], 1);
        list[base + pos] = (int)(p & 0xFFFFFu);
    }
}

// ------------------------------- gathers -----------------------------------
// 32 lanes per node (uint2 = 4 cols/lane), 8 nodes per block.
// Row indices loaded in one parallel lane load, broadcast via shfl; row loads
// issued in independent batches.

__global__ __launch_bounds__(256) void gather_xs_k(const uint2* __restrict__ x4,
                                                   const int* __restrict__ offs,
                                                   const int* __restrict__ list,
                                                   uint2* __restrict__ XS4, int nM) {
    int m = blockIdx.x * 8 + (threadIdx.x >> 5);
    if (m >= nM) return;
    int l = threadIdx.x & 31;
    int s = offs[m], e = offs[m + 1];
    float a0 = 0.f, a1 = 0.f, a2 = 0.f, a3 = 0.f;
    for (int s0 = s; s0 < e; s0 += 32) {
        int cnt = min(e - s0, 32);
        int r = (l < cnt) ? list[s0 + l] : 0;
        for (int i0 = 0; i0 < cnt; i0 += 8) {
            uint2 v[8];
#pragma unroll
            for (int j = 0; j < 8; ++j) {
                int idx = i0 + j;
                int cl = idx < cnt ? idx : cnt - 1;
                int rr = __shfl(r, cl, 32);
                v[j] = x4[(size_t)rr * 32 + l];
            }
#pragma unroll
            for (int j = 0; j < 8; ++j) {
                if (i0 + j < cnt) {
                    a0 += lof(v[j].x); a1 += hif(v[j].x);
                    a2 += lof(v[j].y); a3 += hif(v[j].y);
                }
            }
        }
    }
    uint2 o;
    o.x = (unsigned)f2bf(a0) | ((unsigned)f2bf(a1) << 16);
    o.y = (unsigned)f2bf(a2) | ((unsigned)f2bf(a3) << 16);
    XS4[(size_t)m * 32 + l] = o;
}

// H[m][j] = XS[m]@A1.T + XM[m]@A2.T + XM[m-1]@A3.T + deg[m]*c1[j] + c0[j]
__global__ __launch_bounds__(256) void gemm_h_k(const ushort_t* __restrict__ XSb,
                                                const ushort_t* __restrict__ XMb,
                                                const ushort_t* __restrict__ Wb,
                                                const float* __restrict__ c1,
                                                const float* __restrict__ c0,
                                                const int* __restrict__ off,
                                                ushort_t* __restrict__ Hb, int nM) {
    int wave = threadIdx.x >> 6, lane = threadIdx.x & 63;
    int m0 = blockIdx.x * 64 + wave * 16;
    if (m0 >= nM) return;
    int rl = lane & 15, kg = lane >> 4;
    f32x4 acc[8];
#pragma unroll
    for (int jt = 0; jt < 8; ++jt) acc[jt] = (f32x4){0.f, 0.f, 0.f, 0.f};
    int arow = m0 + rl;
#pragma unroll
    for (int term = 0; term < 3; ++term) {
        const ushort_t* xp = (term == 0) ? XSb : XMb;
        int r2 = (term == 2) ? (arow - 1) : arow;
        bool valid = (r2 >= 0) && (arow < nM);
        const ushort_t* rp = xp + (size_t)r2 * D_IN;
        const ushort_t* wbase = Wb + term * 16384 + rl * 128;
#pragma unroll
        for (int kc = 0; kc < 4; ++kc) {
            int kb = kc * 32 + kg * 8;
            bf16x8 a;
            if (valid) {
                a = *reinterpret_cast<const bf16x8*>(rp + kb);
            } else {
#pragma unroll
                for (int i = 0; i < 8; ++i) a[i] = (__bf16)0.f;
            }
#pragma unroll
            for (int jt = 0; jt < 8; ++jt) {
                bf16x8 b = *reinterpret_cast<const bf16x8*>(wbase + jt * 2048 + kb);
                acc[jt] = __builtin_amdgcn_mfma_f32_16x16x32_bf16(a, b, acc[jt], 0, 0, 0);
            }
        }
    }
    float cc1[8], cc0[8];
#pragma unroll
    for (int jt = 0; jt < 8; ++jt) { cc1[jt] = c1[jt * 16 + rl]; cc0[jt] = c0[jt * 16 + rl]; }
#pragma unroll
    for (int r = 0; r < 4; ++r) {
        int rowd = m0 + kg * 4 + r;
        if (rowd < nM) {
            float degv = (float)(off[rowd + 1] - off[rowd]);
            ushort_t* hp = Hb + (size_t)rowd * D_IN;
#pragma unroll
            for (int jt = 0; jt < 8; ++jt)
                hp[jt * 16 + rl] = f2bf(acc[jt][r] + degv * cc1[jt] + cc0[jt]);
        }
    }
}

// column sums / sum-of-squares for BN
__global__ void bn_stats_k(const ushort_t* __restrict__ Hb, float* __restrict__ bnsum,
                           float* __restrict__ bnsq, int nM) {
    __shared__ float s1[256], s2[256];
    int col = threadIdx.x & 127, half = threadIdx.x >> 7;
    float s = 0.f, q = 0.f;
    for (int m = blockIdx.x * 2 + half; m < nM; m += gridDim.x * 2) {
        float v = bf2f(Hb[(size_t)m * D_IN + col]);
        s += v;
        q += v * v;
    }
    s1[threadIdx.x] = s;
    s2[threadIdx.x] = q;
    __syncthreads();
    if (threadIdx.x < 128) {
        atomicAdd(&bnsum[col], s1[threadIdx.x] + s1[threadIdx.x + 128]);
        atomicAdd(&bnsq[col], s2[threadIdx.x] + s2[threadIdx.x + 128]);
    }
}

// out[n] = scale * sum_{e: src==n} H[dst[e]] + cnt * shift   (BN folded inline)
__global__ __launch_bounds__(256) void gather_out_k(const uint2* __restrict__ H4,
                                                    const int* __restrict__ offs2,
                                                    const int* __restrict__ list,
                                                    const float* __restrict__ bnsum,
                                                    const float* __restrict__ bnsq,
                                                    const float* __restrict__ gamma,
                                                    const float* __restrict__ beta,
                                                    float4* __restrict__ out4,
                                                    int nX, int nM) {
    int n = blockIdx.x * 8 + (threadIdx.x >> 5);
    if (n >= nX) return;
    int l = threadIdx.x & 31;
    int s = offs2[n], e = offs2[n + 1];
    float a0 = 0.f, a1 = 0.f, a2 = 0.f, a3 = 0.f;
    for (int s0 = s; s0 < e; s0 += 32) {
        int cnt = min(e - s0, 32);
        int r = (l < cnt) ? list[s0 + l] : 0;
        for (int i0 = 0; i0 < cnt; i0 += 4) {
            uint2 v[4];
#pragma unroll
            for (int j = 0; j < 4; ++j) {
                int idx = i0 + j;
                int cl = idx < cnt ? idx : cnt - 1;
                int rr = __shfl(r, cl, 32);
                v[j] = H4[(size_t)rr * 32 + l];
            }
#pragma unroll
            for (int j = 0; j < 4; ++j) {
                if (i0 + j < cnt) {
                    a0 += lof(v[j].x); a1 += hif(v[j].x);
                    a2 += lof(v[j].y); a3 += hif(v[j].y);
                }
            }
        }
    }
    float4 s1 = ((const float4*)bnsum)[l];
    float4 s2 = ((const float4*)bnsq)[l];
    float4 g  = ((const float4*)gamma)[l];
    float4 be = ((const float4*)beta)[l];
    float inv = 1.0f / (float)nM;
    float cnt = (float)(e - s);
    float4 o;
    {
        float mean = s1.x * inv, var = s2.x * inv - mean * mean;
        float sc = g.x * rsqrtf(var + BN_EPS);
        o.x = sc * a0 + cnt * (be.x - mean * sc);
    }
    {
        float mean = s1.y * inv, var = s2.y * inv - mean * mean;
        float sc = g.y * rsqrtf(var + BN_EPS);
        o.y = sc * a1 + cnt * (be.y - mean * sc);
    }
    {
        float mean = s1.z * inv, var = s2.z * inv - mean * mean;
        float sc = g.z * rsqrtf(var + BN_EPS);
        o.z = sc * a2 + cnt * (be.z - mean * sc);
    }
    {
        float mean = s1.w * inv, var = s2.w * inv - mean * mean;
        float sc = g.w * rsqrtf(var + BN_EPS);
        o.w = sc * a3 + cnt * (be.w - mean * sc);
    }
    out4[(size_t)n * 32 + l] = o;
}

extern "C" void kernel_launch(void* const* d_in, const int* in_sizes, int n_in,
                              void* d_out, int out_size, void* d_ws, size_t ws_size,
                              hipStream_t stream) {
    const float* x_metrical = (const float*)d_in[0];
    const float* x          = (const float*)d_in[1];
    const int*   edge       = (const int*)d_in[2];
    // d_in[3] = batch (unused: all-zero batch branch)
    const float* Wn    = (const float*)d_in[4];
    const float* bn    = (const float*)d_in[5];
    const float* Wl    = (const float*)d_in[6];
    const float* bl    = (const float*)d_in[7];
    const float* Wr    = (const float*)d_in[8];
    const float* Wo    = (const float*)d_in[9];
    const float* bo    = (const float*)d_in[10];
    const float* gamma = (const float*)d_in[11];
    const float* beta  = (const float*)d_in[12];
    float* out = (float*)d_out;

    int nM = in_sizes[0] / D_IN;
    int nX = in_sizes[1] / D_IN;
    int nE = in_sizes[2] / 2;
    int nTot = nM + nX;
    int nBin = (nTot + 255) >> BIN_SHIFT;    // 977 for 250k; must be <= 1024
    const int* src = edge;        // edge_index[0]
    const int* dst = edge + nE;   // edge_index[1]

    char* ws = (char*)d_ws;
    size_t o = 0;
    auto alloc = [&](size_t bytes) -> void* {
        void* p = ws + o;
        o = (o + bytes + 255) & ~(size_t)255;
        return p;
    };
    ushort_t* Wb        = (ushort_t*)alloc((size_t)3 * 128 * 128 * 2);
    float*    c1        = (float*)alloc(512);
    float*    c0        = (float*)alloc(512);
    float*    bnsum     = (float*)alloc(512);
    float*    bnsq      = (float*)alloc(512);
    int*      binCnt    = (int*)alloc(4096);
    int*      binBase   = (int*)alloc(4104);
    int*      binCursor = (int*)alloc(4096);
    int*      offs      = (int*)alloc(((size_t)nTot + 1) * 4);
    int*      list      = (int*)alloc((size_t)2 * nE * 4);
    // binned aliases XS: binned dead after bucket_sort_k; XS written by gather_xs_k after.
    size_t unionSz = (size_t)2 * nE * 4;
    size_t xsSz = (size_t)nM * D_IN * 2;
    char* uregion = (char*)alloc(unionSz > xsSz ? unionSz : xsSz);
    unsigned* binned = (unsigned*)uregion;
    ushort_t* XSb    = (ushort_t*)uregion;
    ushort_t* xmb    = (ushort_t*)alloc((size_t)nM * D_IN * 2);
    ushort_t* xb     = (ushort_t*)alloc((size_t)nX * D_IN * 2);
    // Hb aliases xb: xb dead after gather_xs_k; Hb written by gemm_h_k after.
    ushort_t* Hb     = xb;

    hipMemsetAsync(binCnt, 0, 4096, stream);
    hipMemsetAsync(bnsum, 0, 1024, stream);  // bnsum + bnsq (adjacent 256B slots)

    combine_weights_k<<<385, 128, 0, stream>>>(Wn, bn, Wl, bl, Wr, Wo, bo, Wb, c1, c0);
    {
        int n8x = nX * D_IN / 8, n8m = nM * D_IN / 8;
        cvt2_k<<<(n8x + n8m + 255) / 256, 256, 0, stream>>>(x, x_metrical, xb, xmb, n8x, n8m);
    }
    bin_hist_k<<<256, 256, 0, stream>>>(src, dst, binCnt, nE, nM, nBin);
    bin_scan_k<<<1, 1024, 0, stream>>>(binCnt, binBase, binCursor, offs, nBin, nTot, 2 * nE);
    bin_scatter_k<<<256, 256, 0, stream>>>(src, dst, binCursor, binned, nE, nM, nBin);
    bucket_sort_k<<<nBin, 256, 0, stream>>>(binned, binBase, offs, list, nTot);
    gather_xs_k<<<(nM + 7) / 8, 256, 0, stream>>>((const uint2*)xb, offs, list,
                                                  (uint2*)XSb, nM);
    gemm_h_k<<<(nM + 63) / 64, 256, 0, stream>>>(XSb, xmb, Wb, c1, c0, offs, Hb, nM);
    bn_stats_k<<<512, 256, 0, stream>>>(Hb, bnsum, bnsq, nM);
    gather_out_k<<<(nX + 7) / 8, 256, 0, stream>>>((const uint2*)Hb, offs + nM, list,
                                                   bnsum, bnsq, gamma, beta,
                                                   (float4*)out, nX, nM);
}

// Round 5
// 228.566 us; speedup vs baseline: 2.0535x; 1.0696x over previous
//
#include <hip/hip_runtime.h>

#define D_IN 128
#define BN_EPS 1e-5f
#define BIN_SHIFT 8            // 256 buckets per bin
#define MAXBIN 1024            // supports nTot <= 262144

typedef __attribute__((ext_vector_type(8))) __bf16 bf16x8;
typedef __attribute__((ext_vector_type(8))) unsigned short ushort8;
typedef __attribute__((ext_vector_type(4))) float f32x4;
typedef unsigned short ushort_t;

__device__ inline ushort_t f2bf(float x) {
    union { float f; unsigned u; } c; c.f = x;
    unsigned r = (c.u + 0x7fffu + ((c.u >> 16) & 1u)) >> 16;  // RNE
    return (ushort_t)r;
}
__device__ inline float bf2f(ushort_t x) {
    union { unsigned u; float f; } c; c.u = ((unsigned)x) << 16;
    return c.f;
}
__device__ inline float lof(unsigned v) {
    union { unsigned u; float f; } c; c.u = v << 16;
    return c.f;
}
__device__ inline float hif(unsigned v) {
    union { unsigned u; float f; } c; c.u = v & 0xffff0000u;
    return c.f;
}

// f32 -> bf16 bulk convert for two arrays in one launch, 8 elems/thread
__global__ void cvt2_k(const float* __restrict__ a, const float* __restrict__ b,
                       ushort_t* __restrict__ oa, ushort_t* __restrict__ ob,
                       int n8a, int n8b) {
    int i = blockIdx.x * blockDim.x + threadIdx.x;
    const float* in; ushort_t* out; int k;
    if (i < n8a) { in = a; out = oa; k = i; }
    else if (i < n8a + n8b) { in = b; out = ob; k = i - n8a; }
    else return;
    float4 f0 = ((const float4*)in)[k * 2];
    float4 f1 = ((const float4*)in)[k * 2 + 1];
    ushort8 o;
    o[0] = f2bf(f0.x); o[1] = f2bf(f0.y); o[2] = f2bf(f0.z); o[3] = f2bf(f0.w);
    o[4] = f2bf(f1.x); o[5] = f2bf(f1.y); o[6] = f2bf(f1.z); o[7] = f2bf(f1.w);
    ((ushort8*)out)[k] = o;
}

// ---------------------------------------------------------------------------
// Folded weights (bf16, row-major [term][j][k]) + bias vectors.
// Block 385 zeroes the accumulators (replaces hipMemsetAsync: tiny graph
// fills cost ~58us each on this harness).
// ---------------------------------------------------------------------------
__global__ void combine_weights_k(const float* __restrict__ Wn, const float* __restrict__ bn,
                                  const float* __restrict__ Wl, const float* __restrict__ bl,
                                  const float* __restrict__ Wr, const float* __restrict__ Wo,
                                  const float* __restrict__ bo,
                                  ushort_t* __restrict__ Wb, float* __restrict__ c1,
                                  float* __restrict__ c0,
                                  int* __restrict__ binCnt, float* __restrict__ bnsum,
                                  float* __restrict__ bnsq) {
    int b = blockIdx.x;
    int j = threadIdx.x;   // 0..127
    if (b < 384) {
        int term = b >> 7;
        int k = b & 127;
        float acc = 0.f;
        if (term == 0) {
            for (int t = 0; t < 128; ++t) acc += Wo[j * 384 + t] * Wn[t * 128 + k];
        } else if (term == 1) {
            acc = Wo[j * 384 + 128 + k];
            for (int t = 0; t < 128; ++t) acc += Wo[j * 384 + 256 + t] * Wr[t * 128 + k];
        } else {
            for (int t = 0; t < 128; ++t) acc += Wo[j * 384 + 256 + t] * Wl[t * 128 + k];
        }
        Wb[term * 16384 + j * 128 + k] = f2bf(acc);
    } else if (b == 384) {
        float a1 = 0.f, a0 = bo[j];
        for (int t = 0; t < 128; ++t) {
            a1 += Wo[j * 384 + t] * bn[t];
            a0 += Wo[j * 384 + 256 + t] * bl[t];
        }
        c1[j] = a1;
        c0[j] = a0;
    } else {
        for (int i = j; i < MAXBIN; i += 128) binCnt[i] = 0;
        bnsum[j] = 0.f;
        bnsq[j] = 0.f;
    }
}

// ------------------- two-level CSR build (counting sort) -------------------
// pair t: key = t<nE ? dst[t] : nM+src[t-nE];  val = t<nE ? src[t] : dst[t-nE]
// bin = key >> BIN_SHIFT.  packed = (localKey << 20) | val   (val < 2^20)

__global__ __launch_bounds__(256) void bin_hist_k(const int* __restrict__ src,
                                                  const int* __restrict__ dst,
                                                  int* __restrict__ binCnt,
                                                  int nE, int nM, int nBin) {
    __shared__ int h[MAXBIN];
    int t = threadIdx.x;
    for (int i = t; i < nBin; i += 256) h[i] = 0;
    __syncthreads();
    int total = 2 * nE;
    int per = (total + gridDim.x - 1) / gridDim.x;
    int lo = blockIdx.x * per, hi = min(lo + per, total);
    for (int i = lo + t; i < hi; i += 256) {
        int key = (i < nE) ? dst[i] : (nM + src[i - nE]);
        atomicAdd(&h[key >> BIN_SHIFT], 1);
    }
    __syncthreads();
    for (int i = t; i < nBin; i += 256) {
        int v = h[i];
        if (v) atomicAdd(&binCnt[i], v);
    }
}

__global__ __launch_bounds__(1024) void bin_scan_k(const int* __restrict__ binCnt,
                                                   int* __restrict__ binBase,
                                                   int* __restrict__ binCursor,
                                                   int* __restrict__ offs,
                                                   int nBin, int nTot, int total2E) {
    __shared__ int sc[1024];
    int t = threadIdx.x;
    int v = (t < nBin) ? binCnt[t] : 0;
    sc[t] = v;
    __syncthreads();
    for (int off = 1; off < 1024; off <<= 1) {
        int a = (t >= off) ? sc[t - off] : 0;
        __syncthreads();
        sc[t] += a;
        __syncthreads();
    }
    int excl = sc[t] - v;
    if (t <= nBin) binBase[t] = excl;          // binBase[nBin] == total
    if (t < nBin) binCursor[t] = excl;
    if (t == nBin) offs[nTot] = total2E;
}

__global__ __launch_bounds__(256) void bin_scatter_k(const int* __restrict__ src,
                                                     const int* __restrict__ dst,
                                                     int* __restrict__ binCursor,
                                                     unsigned* __restrict__ binned,
                                                     int nE, int nM, int nBin) {
    __shared__ int h[MAXBIN];
    __shared__ int base[MAXBIN];
    int t = threadIdx.x;
    for (int i = t; i < nBin; i += 256) h[i] = 0;
    __syncthreads();
    int total = 2 * nE;
    int per = (total + gridDim.x - 1) / gridDim.x;
    int lo = blockIdx.x * per, hi = min(lo + per, total);
    for (int i = lo + t; i < hi; i += 256) {
        int key = (i < nE) ? dst[i] : (nM + src[i - nE]);
        atomicAdd(&h[key >> BIN_SHIFT], 1);
    }
    __syncthreads();
    for (int i = t; i < nBin; i += 256) {
        int c = h[i];
        base[i] = c ? atomicAdd(&binCursor[i], c) : 0;
        h[i] = 0;  // reuse as local cursor
    }
    __syncthreads();
    for (int i = lo + t; i < hi; i += 256) {
        int key, val;
        if (i < nE) { key = dst[i]; val = src[i]; }
        else        { key = nM + src[i - nE]; val = dst[i - nE]; }
        int b = key >> BIN_SHIFT;
        int p = base[b] + atomicAdd(&h[b], 1);
        binned[p] = ((unsigned)(key & ((1 << BIN_SHIFT) - 1)) << 20) | (unsigned)val;
    }
}

// one workgroup per bin: local counting sort -> offs + list
__global__ __launch_bounds__(256) void bucket_sort_k(const unsigned* __restrict__ binned,
                                                     const int* __restrict__ binBase,
                                                     int* __restrict__ offs,
                                                     int* __restrict__ list, int nTot) {
    __shared__ int hist[256];
    __shared__ int sc[256];
    __shared__ int cur[256];
    int b = blockIdx.x;
    int base = binBase[b], end = binBase[b + 1];
    int n = end - base;
    int t = threadIdx.x;
    hist[t] = 0;
    __syncthreads();
    for (int i = t; i < n; i += 256) atomicAdd(&hist[binned[base + i] >> 20], 1);
    __syncthreads();
    int v = hist[t];
    sc[t] = v;
    __syncthreads();
    for (int off = 1; off < 256; off <<= 1) {
        int a = (t >= off) ? sc[t - off] : 0;
        __syncthreads();
        sc[t] += a;
        __syncthreads();
    }
    int excl = sc[t] - v;
    int bucket = (b << BIN_SHIFT) + t;
    if (bucket < nTot) offs[bucket] = base + excl;
    cur[t] = excl;
    __syncthreads();
    for (int i = t; i < n; i += 256) {
        unsigned p = binned[base + i];
        int lb = p >> 20;
        int pos = atomicAdd(&cur[lb], 1);
        list[base + pos] = (int)(p & 0xFFFFFu);
    }
}

// ------------------------------- gathers -----------------------------------

__global__ __launch_bounds__(256) void gather_xs_k(const uint2* __restrict__ x4,
                                                   const int* __restrict__ offs,
                                                   const int* __restrict__ list,
                                                   uint2* __restrict__ XS4, int nM) {
    int m = blockIdx.x * 8 + (threadIdx.x >> 5);
    if (m >= nM) return;
    int l = threadIdx.x & 31;
    int s = offs[m], e = offs[m + 1];
    float a0 = 0.f, a1 = 0.f, a2 = 0.f, a3 = 0.f;
    for (int s0 = s; s0 < e; s0 += 32) {
        int cnt = min(e - s0, 32);
        int r = (l < cnt) ? list[s0 + l] : 0;
        for (int i0 = 0; i0 < cnt; i0 += 8) {
            uint2 v[8];
#pragma unroll
            for (int j = 0; j < 8; ++j) {
                int idx = i0 + j;
                int cl = idx < cnt ? idx : cnt - 1;
                int rr = __shfl(r, cl, 32);
                v[j] = x4[(size_t)rr * 32 + l];
            }
#pragma unroll
            for (int j = 0; j < 8; ++j) {
                if (i0 + j < cnt) {
                    a0 += lof(v[j].x); a1 += hif(v[j].x);
                    a2 += lof(v[j].y); a3 += hif(v[j].y);
                }
            }
        }
    }
    uint2 o;
    o.x = (unsigned)f2bf(a0) | ((unsigned)f2bf(a1) << 16);
    o.y = (unsigned)f2bf(a2) | ((unsigned)f2bf(a3) << 16);
    XS4[(size_t)m * 32 + l] = o;
}

// H[m][j] = XS[m]@A1.T + XM[m]@A2.T + XM[m-1]@A3.T + deg[m]*c1[j] + c0[j]
// + fused BN column sum / sum-of-squares (wave shfl reduce -> LDS -> atomic).
// NOTE: no early wave return — tail block waves must reach __syncthreads.
__global__ __launch_bounds__(256) void gemm_h_k(const ushort_t* __restrict__ XSb,
                                                const ushort_t* __restrict__ XMb,
                                                const ushort_t* __restrict__ Wb,
                                                const float* __restrict__ c1,
                                                const float* __restrict__ c0,
                                                const int* __restrict__ off,
                                                ushort_t* __restrict__ Hb,
                                                float* __restrict__ bnsum,
                                                float* __restrict__ bnsq, int nM) {
    __shared__ float lds_s[4][128];
    __shared__ float lds_q[4][128];
    int wave = threadIdx.x >> 6, lane = threadIdx.x & 63;
    int m0 = blockIdx.x * 64 + wave * 16;
    int rl = lane & 15, kg = lane >> 4;
    f32x4 acc[8];
#pragma unroll
    for (int jt = 0; jt < 8; ++jt) acc[jt] = (f32x4){0.f, 0.f, 0.f, 0.f};
    int arow = m0 + rl;
    bool wave_live = (m0 < nM);
    if (wave_live) {
#pragma unroll
        for (int term = 0; term < 3; ++term) {
            const ushort_t* xp = (term == 0) ? XSb : XMb;
            int r2 = (term == 2) ? (arow - 1) : arow;
            bool valid = (r2 >= 0) && (arow < nM);
            const ushort_t* rp = xp + (size_t)r2 * D_IN;
            const ushort_t* wbase = Wb + term * 16384 + rl * 128;
#pragma unroll
            for (int kc = 0; kc < 4; ++kc) {
                int kb = kc * 32 + kg * 8;
                bf16x8 a;
                if (valid) {
                    a = *reinterpret_cast<const bf16x8*>(rp + kb);
                } else {
#pragma unroll
                    for (int i = 0; i < 8; ++i) a[i] = (__bf16)0.f;
                }
#pragma unroll
                for (int jt = 0; jt < 8; ++jt) {
                    bf16x8 b = *reinterpret_cast<const bf16x8*>(wbase + jt * 2048 + kb);
                    acc[jt] = __builtin_amdgcn_mfma_f32_16x16x32_bf16(a, b, acc[jt], 0, 0, 0);
                }
            }
        }
    }
    float ssum[8], sq[8];
#pragma unroll
    for (int jt = 0; jt < 8; ++jt) { ssum[jt] = 0.f; sq[jt] = 0.f; }
    if (wave_live) {
        float cc1[8], cc0[8];
#pragma unroll
        for (int jt = 0; jt < 8; ++jt) { cc1[jt] = c1[jt * 16 + rl]; cc0[jt] = c0[jt * 16 + rl]; }
#pragma unroll
        for (int r = 0; r < 4; ++r) {
            int rowd = m0 + kg * 4 + r;
            if (rowd < nM) {
                float degv = (float)(off[rowd + 1] - off[rowd]);
                ushort_t* hp = Hb + (size_t)rowd * D_IN;
#pragma unroll
                for (int jt = 0; jt < 8; ++jt) {
                    float hv = acc[jt][r] + degv * cc1[jt] + cc0[jt];
                    hp[jt * 16 + rl] = f2bf(hv);
                    ssum[jt] += hv;
                    sq[jt] += hv * hv;
                }
            }
        }
    }
    // reduce across the 4 kg groups (lanes rl, rl+16, rl+32, rl+48)
#pragma unroll
    for (int jt = 0; jt < 8; ++jt) {
        ssum[jt] += __shfl_xor(ssum[jt], 16, 64);
        ssum[jt] += __shfl_xor(ssum[jt], 32, 64);
        sq[jt]   += __shfl_xor(sq[jt], 16, 64);
        sq[jt]   += __shfl_xor(sq[jt], 32, 64);
    }
    if (lane < 16) {
#pragma unroll
        for (int jt = 0; jt < 8; ++jt) {
            lds_s[wave][jt * 16 + rl] = ssum[jt];
            lds_q[wave][jt * 16 + rl] = sq[jt];
        }
    }
    __syncthreads();
    if (threadIdx.x < 128) {
        int col = threadIdx.x;
        float s = lds_s[0][col] + lds_s[1][col] + lds_s[2][col] + lds_s[3][col];
        float q = lds_q[0][col] + lds_q[1][col] + lds_q[2][col] + lds_q[3][col];
        atomicAdd(&bnsum[col], s);
        atomicAdd(&bnsq[col], q);
    }
}

// out[n] = scale * sum_{e: src==n} H[dst[e]] + cnt * shift   (BN folded inline)
__global__ __launch_bounds__(256) void gather_out_k(const uint2* __restrict__ H4,
                                                    const int* __restrict__ offs2,
                                                    const int* __restrict__ list,
                                                    const float* __restrict__ bnsum,
                                                    const float* __restrict__ bnsq,
                                                    const float* __restrict__ gamma,
                                                    const float* __restrict__ beta,
                                                    float4* __restrict__ out4,
                                                    int nX, int nM) {
    int n = blockIdx.x * 8 + (threadIdx.x >> 5);
    if (n >= nX) return;
    int l = threadIdx.x & 31;
    int s = offs2[n], e = offs2[n + 1];
    float a0 = 0.f, a1 = 0.f, a2 = 0.f, a3 = 0.f;
    for (int s0 = s; s0 < e; s0 += 32) {
        int cnt = min(e - s0, 32);
        int r = (l < cnt) ? list[s0 + l] : 0;
        for (int i0 = 0; i0 < cnt; i0 += 4) {
            uint2 v[4];
#pragma unroll
            for (int j = 0; j < 4; ++j) {
                int idx = i0 + j;
                int cl = idx < cnt ? idx : cnt - 1;
                int rr = __shfl(r, cl, 32);
                v[j] = H4[(size_t)rr * 32 + l];
            }
#pragma unroll
            for (int j = 0; j < 4; ++j) {
                if (i0 + j < cnt) {
                    a0 += lof(v[j].x); a1 += hif(v[j].x);
                    a2 += lof(v[j].y); a3 += hif(v[j].y);
                }
            }
        }
    }
    float4 s1 = ((const float4*)bnsum)[l];
    float4 s2 = ((const float4*)bnsq)[l];
    float4 g  = ((const float4*)gamma)[l];
    float4 be = ((const float4*)beta)[l];
    float inv = 1.0f / (float)nM;
    float cnt = (float)(e - s);
    float4 o;
    {
        float mean = s1.x * inv, var = s2.x * inv - mean * mean;
        float sc = g.x * rsqrtf(var + BN_EPS);
        o.x = sc * a0 + cnt * (be.x - mean * sc);
    }
    {
        float mean = s1.y * inv, var = s2.y * inv - mean * mean;
        float sc = g.y * rsqrtf(var + BN_EPS);
        o.y = sc * a1 + cnt * (be.y - mean * sc);
    }
    {
        float mean = s1.z * inv, var = s2.z * inv - mean * mean;
        float sc = g.z * rsqrtf(var + BN_EPS);
        o.z = sc * a2 + cnt * (be.z - mean * sc);
    }
    {
        float mean = s1.w * inv, var = s2.w * inv - mean * mean;
        float sc = g.w * rsqrtf(var + BN_EPS);
        o.w = sc * a3 + cnt * (be.w - mean * sc);
    }
    out4[(size_t)n * 32 + l] = o;
}

extern "C" void kernel_launch(void* const* d_in, const int* in_sizes, int n_in,
                              void* d_out, int out_size, void* d_ws, size_t ws_size,
                              hipStream_t stream) {
    const float* x_metrical = (const float*)d_in[0];
    const float* x          = (const float*)d_in[1];
    const int*   edge       = (const int*)d_in[2];
    // d_in[3] = batch (unused: all-zero batch branch)
    const float* Wn    = (const float*)d_in[4];
    const float* bn    = (const float*)d_in[5];
    const float* Wl    = (const float*)d_in[6];
    const float* bl    = (const float*)d_in[7];
    const float* Wr    = (const float*)d_in[8];
    const float* Wo    = (const float*)d_in[9];
    const float* bo    = (const float*)d_in[10];
    const float* gamma = (const float*)d_in[11];
    const float* beta  = (const float*)d_in[12];
    float* out = (float*)d_out;

    int nM = in_sizes[0] / D_IN;
    int nX = in_sizes[1] / D_IN;
    int nE = in_sizes[2] / 2;
    int nTot = nM + nX;
    int nBin = (nTot + 255) >> BIN_SHIFT;    // 977 for 250k; must be <= 1024
    const int* src = edge;        // edge_index[0]
    const int* dst = edge + nE;   // edge_index[1]

    char* ws = (char*)d_ws;
    size_t o = 0;
    auto alloc = [&](size_t bytes) -> void* {
        void* p = ws + o;
        o = (o + bytes + 255) & ~(size_t)255;
        return p;
    };
    ushort_t* Wb        = (ushort_t*)alloc((size_t)3 * 128 * 128 * 2);
    float*    c1        = (float*)alloc(512);
    float*    c0        = (float*)alloc(512);
    float*    bnsum     = (float*)alloc(512);
    float*    bnsq      = (float*)alloc(512);
    int*      binCnt    = (int*)alloc(4096);
    int*      binBase   = (int*)alloc(4104);
    int*      binCursor = (int*)alloc(4096);
    int*      offs      = (int*)alloc(((size_t)nTot + 1) * 4);
    int*      list      = (int*)alloc((size_t)2 * nE * 4);
    // binned aliases XS: binned dead after bucket_sort_k; XS written after.
    size_t unionSz = (size_t)2 * nE * 4;
    size_t xsSz = (size_t)nM * D_IN * 2;
    char* uregion = (char*)alloc(unionSz > xsSz ? unionSz : xsSz);
    unsigned* binned = (unsigned*)uregion;
    ushort_t* XSb    = (ushort_t*)uregion;
    ushort_t* xmb    = (ushort_t*)alloc((size_t)nM * D_IN * 2);
    ushort_t* xb     = (ushort_t*)alloc((size_t)nX * D_IN * 2);
    // Hb aliases xb: xb dead after gather_xs_k; Hb written by gemm_h_k after.
    ushort_t* Hb     = xb;

    // combine_weights_k block 385 zeroes binCnt/bnsum/bnsq (no memsets).
    combine_weights_k<<<386, 128, 0, stream>>>(Wn, bn, Wl, bl, Wr, Wo, bo, Wb, c1, c0,
                                               binCnt, bnsum, bnsq);
    {
        int n8x = nX * D_IN / 8, n8m = nM * D_IN / 8;
        cvt2_k<<<(n8x + n8m + 255) / 256, 256, 0, stream>>>(x, x_metrical, xb, xmb, n8x, n8m);
    }
    bin_hist_k<<<256, 256, 0, stream>>>(src, dst, binCnt, nE, nM, nBin);
    bin_scan_k<<<1, 1024, 0, stream>>>(binCnt, binBase, binCursor, offs, nBin, nTot, 2 * nE);
    bin_scatter_k<<<256, 256, 0, stream>>>(src, dst, binCursor, binned, nE, nM, nBin);
    bucket_sort_k<<<nBin, 256, 0, stream>>>(binned, binBase, offs, list, nTot);
    gather_xs_k<<<(nM + 7) / 8, 256, 0, stream>>>((const uint2*)xb, offs, list,
                                                  (uint2*)XSb, nM);
    gemm_h_k<<<(nM + 63) / 64, 256, 0, stream>>>(XSb, xmb, Wb, c1, c0, offs, Hb,
                                                 bnsum, bnsq, nM);
    gather_out_k<<<(nX + 7) / 8, 256, 0, stream>>>((const uint2*)Hb, offs + nM, list,
                                                   bnsum, bnsq, gamma, beta,
                                                   (float4*)out, nX, nM);
}